// Round 2
// baseline (238.628 us; speedup 1.0000x reference)
//
#include <hip/hip_runtime.h>

// Chunked fast-weight linear attention, MI355X gfx950.
// grid = 32 bh * 8 vgroups = 256 wgs (1/CU), 512 threads (8 waves).
// R2: (1) T14 reg-prefetch of next chunk's q/k/v (hide HBM latency under
//     compute), (2) swizzle key (row^(row>>3))&7 fixes fragkT 8-way bank
//     conflicts, (3) q@W_prev moved into phase1 (shorter post-B3 tail).

typedef _Float16 f16;
typedef __attribute__((ext_vector_type(4))) _Float16 f16x4;
typedef __attribute__((ext_vector_type(8))) _Float16 f16x8;
typedef __attribute__((ext_vector_type(4))) float f32x4;
typedef __attribute__((ext_vector_type(4))) float fv4;

#define MFMA16(a, b, c) __builtin_amdgcn_mfma_f32_16x16x32_f16((a), (b), (c), 0, 0, 0)

// Byte offset into a row-major [*][128] f16 LDS tile.
// XOR key mixes row bits 0-2 AND 3-5 so column reads (fragkT: rows j,8+j,
// 16+j,24+j) land in distinct 16B slots. Bijective per row; consistent
// across all writers/readers -> layout-correct by construction.
__device__ __forceinline__ int swzb(int row, int col) {
  int s = (row ^ (row >> 3)) & 7;
  return (row << 8) + ((col << 1) ^ (s << 4));
}

// 8-f16 MFMA operand fragment. k-map: k = 8*(lane>>4) + j, applied to BOTH
// A and B operands of every MFMA -> any bijective per-(group,reg) k-map
// yields the correct contraction. One ds_read_b128 per fragment.
__device__ __forceinline__ f16x8 fragr(const f16* lds, int row, int kbase, int lane) {
  int c0 = kbase + ((lane >> 4) << 3);
  return *(const f16x8*)((const char*)lds + swzb(row, c0));
}

// Transposed fragment (B operand of the state update): element j from
// k_lds[kbase + 8*(lane>>4) + j][col]. 8 scalar reads, now ~2-way banked.
__device__ __forceinline__ f16x8 fragkT(const f16* lds, int kbase, int col, int lane) {
  f16x8 r;
  int r0 = kbase + ((lane >> 4) << 3);
#pragma unroll
  for (int j = 0; j < 8; ++j)
    r[j] = *(const f16*)((const char*)lds + swzb(r0 + j, col));
  return r;
}

__global__ __launch_bounds__(512, 1)
void ttr_fastweight(const float* __restrict__ q, const float* __restrict__ k,
                    const float* __restrict__ v, float* __restrict__ out) {
  __shared__ f16 q_lds[128 * 128];      // 32 KB
  __shared__ f16 k_lds[128 * 128];      // 32 KB
  __shared__ f16 a_lds[128 * 128];      // 32 KB (masked scores, f16)
  __shared__ f16 vT_lds[16 * 128];      // 4 KB  (v slice, transposed)
  __shared__ f16 wT_lds[2][16 * 128];   // 8 KB  (state W^T, double-buffered)

  const int tid = threadIdx.x;
  const int lane = tid & 63;
  const int wave = tid >> 6;
  const int vg = blockIdx.x >> 5;   // 0..7  (v-column group of 16)
  const int b = blockIdx.x & 31;    // 0..31 (batch-head); same b -> same XCD

  const float* qb = q + (size_t)b * (4096 * 128);
  const float* kb = k + (size_t)b * (4096 * 128);
  const float* vb = v + (size_t)b * (4096 * 128) + vg * 16;
  float* ob = out + (size_t)b * (4096 * 128) + vg * 16;

  for (int i = tid; i < 16 * 128; i += 512) wT_lds[0][i] = (f16)0.f;

  f32x4 wacc = {0.f, 0.f, 0.f, 0.f};  // running W^T tile: [16v] x [16f of wave]

  const int colj = lane & 15;          // MFMA n/col (and A-operand row) index
  const int row4 = (lane >> 4) << 2;   // MFMA C/D row base: row = row4 + reg

  // staging address split (constant per thread)
  const int rr = tid >> 5;             // 0..15
  const int cc = (tid & 31) << 2;      // 0..124
  const int vrow = tid >> 2;           // 0..127
  const int vp = (tid & 3) << 2;       // 0,4,8,12

  // ---- T14 prefetch registers: next chunk's q/k/v held in VGPRs ----
  fv4 pq[8], pk[8], pv;
#define ISSUE_PF(CH)                                                     \
  {                                                                      \
    const float* qg = qb + (size_t)(CH) * (128 * 128);                   \
    const float* kg = kb + (size_t)(CH) * (128 * 128);                   \
    const float* vgp = vb + (size_t)(CH) * (128 * 128);                  \
    _Pragma("unroll") for (int p = 0; p < 8; ++p) {                      \
      int row = (p << 4) + rr;                                           \
      pq[p] = *(const fv4*)(qg + row * 128 + cc);                        \
      pk[p] = *(const fv4*)(kg + row * 128 + cc);                        \
    }                                                                    \
    pv = *(const fv4*)(vgp + vrow * 128 + vp);                           \
  }

  ISSUE_PF(0);
  __syncthreads();  // covers wT zero-init

  for (int chunk = 0; chunk < 32; ++chunk) {
    const int cur = chunk & 1, nxt = cur ^ 1;

    // ---------------- write prefetched q,k,v (f32 -> f16, swizzled) -------
#pragma unroll
    for (int p = 0; p < 8; ++p) {
      int row = (p << 4) + rr;
      f16x4 h = {(f16)pq[p][0], (f16)pq[p][1], (f16)pq[p][2], (f16)pq[p][3]};
      *(f16x4*)((char*)q_lds + swzb(row, cc)) = h;
      f16x4 h2 = {(f16)pk[p][0], (f16)pk[p][1], (f16)pk[p][2], (f16)pk[p][3]};
      *(f16x4*)((char*)k_lds + swzb(row, cc)) = h2;
    }
#pragma unroll
    for (int t = 0; t < 4; ++t)
      *(f16*)((char*)vT_lds + swzb(vp + t, vrow)) = (f16)pv[t];
    __syncthreads();  // B2: staged data visible

    // ---- issue next chunk's global loads; waited at next loop top ----
    if (chunk < 31) ISSUE_PF(chunk + 1);

    // ------- phase 1: A tiles (causal) + q@W_prev + state update -------
    f32x4 oacc = {0.f, 0.f, 0.f, 0.f};  // out accumulator (q@W_prev part)
    {
      int u = 0;
      for (int r = 0; r < 8; ++r) {
        for (int c = 0; c <= r; ++c) {
          if ((u++ & 7) != wave) continue;   // 36 tiles round-robin over 8 waves
          f32x4 acc = {0.f, 0.f, 0.f, 0.f};
          int arow = (r << 4) + colj;
          int brow = (c << 4) + colj;
#pragma unroll
          for (int kk = 0; kk < 4; ++kk)
            acc = MFMA16(fragr(q_lds, arow, kk << 5, lane),
                         fragr(k_lds, brow, kk << 5, lane), acc);
#pragma unroll
          for (int t = 0; t < 4; ++t) {
            float val = acc[t];
            if (r == c && colj > row4 + t) val = 0.f;  // inclusive causal mask
            *(f16*)((char*)a_lds + swzb((r << 4) + row4 + t, (c << 4) + colj)) =
                (f16)val;
          }
        }
      }
      // zero the half-K garbage tile (even r uses K past the diagonal)
      if (wave < 4) {
        int r = wave << 1;
#pragma unroll
        for (int t = 0; t < 4; ++t)
          *(f16*)((char*)a_lds +
                  swzb((r << 4) + row4 + t, ((r + 1) << 4) + colj)) = (f16)0.f;
      }
      // inter-chunk output: q @ W_prev (wT_lds[cur] as B operand)
      {
        int qrow = (wave << 4) + colj;
#pragma unroll
        for (int kk = 0; kk < 4; ++kk)
          oacc = MFMA16(fragr(q_lds, qrow, kk << 5, lane),
                        fragr(wT_lds[cur], colj, kk << 5, lane), oacc);
      }
      // state update: W^T[v][f] += sum_j vT[v][j] * k[j][f]; wave owns f-tile
#pragma unroll
      for (int kk = 0; kk < 4; ++kk)
        wacc = MFMA16(fragr(vT_lds, colj, kk << 5, lane),
                      fragkT(k_lds, kk << 5, (wave << 4) + colj, lane), wacc);
#pragma unroll
      for (int t = 0; t < 4; ++t)
        *(f16*)((char*)wT_lds[nxt] + swzb(row4 + t, (wave << 4) + colj)) =
            (f16)wacc[t];
    }
    __syncthreads();  // B3: a_lds visible

    // ------------- phase 2: out += A@v, scale, store -------------
    {
      int r = wave;
      int qrow = (r << 4) + colj;
      int nkk = (r + 2) >> 1;         // ceil((r+1)/2) K-steps of 32
      f32x4 acc = oacc;
      for (int kk = 0; kk < nkk; ++kk)  // intra-chunk: A @ v
        acc = MFMA16(fragr(a_lds, qrow, kk << 5, lane),
                     fragr(vT_lds, colj, kk << 5, lane), acc);
      float* og = ob + (size_t)((chunk << 7) + (r << 4)) * 128 + colj;
#pragma unroll
      for (int t = 0; t < 4; ++t) {
        int lr = row4 + t;
        float tg = (float)((chunk << 7) + (r << 4) + lr + 1);
        og[(size_t)lr * 128] = acc[t] / tg;
      }
    }
    __syncthreads();  // B1: phase-2 reads done before next chunk's LDS writes
  }
}

extern "C" void kernel_launch(void* const* d_in, const int* in_sizes, int n_in,
                              void* d_out, int out_size, void* d_ws, size_t ws_size,
                              hipStream_t stream) {
  const float* q = (const float*)d_in[0];
  const float* k = (const float*)d_in[1];
  const float* v = (const float*)d_in[2];
  float* o = (float*)d_out;
  // chunk_size (d_in[3]) is fixed at 128 for this problem shape.
  ttr_fastweight<<<dim3(256), dim3(512), 0, stream>>>(q, k, v, o);
}

// Round 3
// 112.534 us; speedup vs baseline: 2.1205x; 2.1205x over previous
//
#include <hip/hip_runtime.h>

// Chunked fast-weight linear attention, MI355X gfx950 — 3-kernel decomposition.
// K1 ttr_pt:     P_c = k_c^T v_c per (bh,chunk)            [1024 wgs, parallel]
// K2 ttr_prefix: W_c = sum_{c'<c} P_c' (exclusive prefix)  [256 wgs, parallel in (v,f)]
// K3 ttr_out:    out = mask(q k^T) v + q W_prev, /t        [2048 wgs, parallel]
// W stored in MFMA-B-fragment-permuted layout so K3 loads it straight from
// global memory with coalesced b128s (no LDS staging for W).
// Fallback: single-kernel R1 implementation if ws_size < 64 MB.

typedef _Float16 f16;
typedef __attribute__((ext_vector_type(4))) _Float16 f16x4;
typedef __attribute__((ext_vector_type(8))) _Float16 f16x8;
typedef __attribute__((ext_vector_type(4))) float f32x4;
typedef __attribute__((ext_vector_type(16))) float f32x16;
typedef __attribute__((ext_vector_type(4))) float fv4;

#define MFMA16(a, b, c) __builtin_amdgcn_mfma_f32_16x16x32_f16((a), (b), (c), 0, 0, 0)
#define MFMA32(a, b, c) __builtin_amdgcn_mfma_f32_32x32x16_f16((a), (b), (c), 0, 0, 0)

// Byte offset into a row-major [*][128] f16 LDS tile; XOR key mixes row bits
// 0-2 and 3-5 so both 16-row and 32-row fragment reads spread evenly over
// banks. Consistent across all writers/readers -> layout-correct.
__device__ __forceinline__ int swzb(int row, int col) {
  int s = (row ^ (row >> 3)) & 7;
  return (row << 8) + ((col << 1) ^ (s << 4));
}

// 32x32x16 operand fragment: row = lane&31, k = kk*16 + 8*(lane>>5) + j.
// Same k-map on A and B operands -> contraction correct. One ds_read_b128.
__device__ __forceinline__ f16x8 frag32(const f16* lds, int row, int kk, int lane) {
  int c0 = (kk << 4) + ((lane >> 5) << 3);
  return *(const f16x8*)((const char*)lds + swzb(row, c0));
}

// 32x32 C/D row for acc reg r, lane-half g: row=(r&3)+8*(r>>2)+4*g  [m74/m101]
__device__ __forceinline__ int rowf(int r, int g) {
  return (r & 3) + ((r >> 2) << 3) + (g << 2);
}

// ---------------------------------------------------------------------------
// K1: P_c^T[v][f] = sum_s v[s][v] * k[s][f]  (A = v^T staged, B^T = k^T staged)
__global__ __launch_bounds__(512, 1)
void ttr_pt(const float* __restrict__ k, const float* __restrict__ v,
            f16* __restrict__ pt) {
  __shared__ f16 kT[128 * 128];  // k^T[f][s]
  __shared__ f16 vT[128 * 128];  // v^T[v][s]
  const int tid = threadIdx.x, lane = tid & 63, wave = tid >> 6;
  const int bh = blockIdx.x >> 5, c = blockIdx.x & 31;
  const float* kg = k + ((size_t)bh * 4096 + c * 128) * 128;
  const float* vg = v + ((size_t)bh * 4096 + c * 128) * 128;
  const int f0 = (tid & 31) << 2;
#pragma unroll
  for (int p = 0; p < 8; ++p) {
    int s = (p << 4) + (tid >> 5);
    fv4 xk = *(const fv4*)(kg + s * 128 + f0);
    fv4 xv = *(const fv4*)(vg + s * 128 + f0);
#pragma unroll
    for (int e = 0; e < 4; ++e) {
      *(f16*)((char*)kT + swzb(f0 + e, s)) = (f16)xk[e];
      *(f16*)((char*)vT + swzb(f0 + e, s)) = (f16)xv[e];
    }
  }
  __syncthreads();
  const int l31 = lane & 31, g = lane >> 5;
  const int mt = wave >> 1, nt0 = (wave & 1) << 1;  // wave -> (v-tile, 2 f-tiles)
  f32x16 p0 = {0.f}, p1 = {0.f};
#pragma unroll
  for (int kk = 0; kk < 8; ++kk) {
    f16x8 a = frag32(vT, (mt << 5) + l31, kk, lane);
    p0 = MFMA32(a, frag32(kT, (nt0 << 5) + l31, kk, lane), p0);
    p1 = MFMA32(a, frag32(kT, ((nt0 + 1) << 5) + l31, kk, lane), p1);
  }
  // store P^T row-major [v][f] f16 (64B-contiguous per reg per lane-half)
  f16* dst = pt + (size_t)blockIdx.x * 16384;
#pragma unroll
  for (int r = 0; r < 16; ++r) {
    int vr = (mt << 5) + rowf(r, g);
    dst[vr * 128 + (nt0 << 5) + l31] = (f16)p0[r];
    dst[vr * 128 + ((nt0 + 1) << 5) + l31] = (f16)p1[r];
  }
}

// ---------------------------------------------------------------------------
// K2: exclusive prefix over chunks; output in B-frag-permuted layout:
// 16B unit (NT,kk,g,laneC) holds W[v=NT*32+laneC][f=kk*16+8g .. +7].
// wg = (bh, 16-row v-slice); thread owns 8 f16 of the slice.
__global__ __launch_bounds__(256, 1)
void ttr_prefix(const f16* __restrict__ pt, f16* __restrict__ w) {
  __shared__ f16 xch[256 * 8];  // 4KB reblock buffer
  const int tid = threadIdx.x;
  const int bh = blockIdx.x >> 3, vs = blockIdx.x & 7;
  const int v0 = vs << 4;
  const int NT = v0 >> 5;
  const int vloc = tid >> 4, fblk = tid & 15;
  const size_t bhbase = (size_t)bh * 32 * 16384;
  const f16* src = pt + bhbase + (size_t)(v0 + vloc) * 128 + fblk * 8;
  // write-side decomposition of tid -> (kk, g, laneC-within-slice)
  const int kk = tid >> 5, gg = (tid >> 4) & 1, lc = tid & 15;
  f16* dstu = w + bhbase +
              (size_t)(((NT * 8 + kk) * 64) + gg * 32 + (v0 & 31) + lc) * 8;
  // LDS swizzle phi(u) = (u>>4)*16 + ((u&15)^(u>>4)) — bijective, bank-even
  const int phi_w = vloc * 16 + (fblk ^ vloc);
  const int phi_r = lc * 16 + ((tid >> 4) ^ lc);
  float acc[8];
#pragma unroll
  for (int e = 0; e < 8; ++e) acc[e] = 0.f;
  for (int c = 0; c < 32; ++c) {
    f16x8 pcur = *(const f16x8*)(src + (size_t)c * 16384);  // issue early
    f16x8 h;
#pragma unroll
    for (int e = 0; e < 8; ++e) h[e] = (f16)acc[e];
    *(f16x8*)(xch + phi_w * 8) = h;
    __syncthreads();
    f16x8 o = *(const f16x8*)(xch + phi_r * 8);
    *(f16x8*)(dstu + (size_t)c * 16384) = o;  // exclusive prefix (W[0]=0)
    __syncthreads();
#pragma unroll
    for (int e = 0; e < 8; ++e) acc[e] += (float)pcur[e];
  }
}

// ---------------------------------------------------------------------------
// K3: out[c*128+i][n] = ( q_i . W_prev[:,n] + sum_{j<=i} S[i][j] v[j][n] ) / t
// wg = (bh, c, vhalf); 4 waves; LDS 80KB -> 2 wgs/CU.
__global__ __launch_bounds__(256, 1)
void ttr_out(const float* __restrict__ q, const float* __restrict__ k,
             const float* __restrict__ v, const f16* __restrict__ w,
             float* __restrict__ out) {
  __shared__ f16 q_lds[128 * 128];  // 32KB
  __shared__ f16 s_lds[128 * 128];  // 32KB: k, then masked S
  __shared__ f16 vT[64 * 128];      // 16KB: v-half transposed
  const int tid = threadIdx.x, lane = tid & 63, wave = tid >> 6;
  const int l31 = lane & 31, g = lane >> 5;
  const int vhalf = blockIdx.x >> 10;           // pairs 1024 apart -> same XCD
  const int bhc = blockIdx.x & 1023;
  const int bh = bhc >> 5, c = bhc & 31;
  const float* qg = q + ((size_t)bh * 4096 + c * 128) * 128;
  const float* kg = k + ((size_t)bh * 4096 + c * 128) * 128;
  const float* vg = v + ((size_t)bh * 4096 + c * 128) * 128 + vhalf * 64;

  // W B-frags straight from global (permuted layout) — issue before staging
  const f16* wb = w + (size_t)bhc * 16384;
  f16x8 wf0[8], wf1[8];
#pragma unroll
  for (int kk = 0; kk < 8; ++kk) {
    int NT = vhalf * 2;
    wf0[kk] = *(const f16x8*)(wb + (size_t)(((NT * 8 + kk) * 64) + lane) * 8);
    wf1[kk] = *(const f16x8*)(wb + (size_t)((((NT + 1) * 8 + kk) * 64) + lane) * 8);
  }
  // stage q, k (f32 -> f16, swizzled)
  const int f0 = (tid & 31) << 2;
#pragma unroll
  for (int p = 0; p < 16; ++p) {
    int s = (p << 3) + (tid >> 5);
    fv4 xq = *(const fv4*)(qg + s * 128 + f0);
    f16x4 hq = {(f16)xq[0], (f16)xq[1], (f16)xq[2], (f16)xq[3]};
    *(f16x4*)((char*)q_lds + swzb(s, f0)) = hq;
    fv4 xk = *(const fv4*)(kg + s * 128 + f0);
    f16x4 hk = {(f16)xk[0], (f16)xk[1], (f16)xk[2], (f16)xk[3]};
    *(f16x4*)((char*)s_lds + swzb(s, f0)) = hk;
  }
  // stage vT (transposed scalar writes)
  const int c0 = (tid & 15) << 2;
#pragma unroll
  for (int p = 0; p < 8; ++p) {
    int s = (p << 4) + (tid >> 4);
    fv4 xv = *(const fv4*)(vg + s * 128 + c0);
#pragma unroll
    for (int e = 0; e < 4; ++e)
      *(f16*)((char*)vT + swzb(c0 + e, s)) = (f16)xv[e];
  }
  __syncthreads();  // B1

  // causal-triangle S tiles (10 of 16), round-robined across waves
  int mts[3], jts[3], ntiles;
  switch (wave) {
    case 0:  mts[0]=0; jts[0]=0; mts[1]=2; jts[1]=1; mts[2]=3; jts[2]=2; ntiles=3; break;
    case 1:  mts[0]=1; jts[0]=0; mts[1]=2; jts[1]=2; mts[2]=3; jts[2]=3; ntiles=3; break;
    case 2:  mts[0]=1; jts[0]=1; mts[1]=3; jts[1]=0; mts[2]=0; jts[2]=0; ntiles=2; break;
    default: mts[0]=2; jts[0]=0; mts[1]=3; jts[1]=1; mts[2]=0; jts[2]=0; ntiles=2; break;
  }
  f32x16 sa0 = {0.f}, sa1 = {0.f}, sa2 = {0.f};
  f32x16 o0 = {0.f}, o1 = {0.f};
#pragma unroll
  for (int kk = 0; kk < 8; ++kk) {
    sa0 = MFMA32(frag32(q_lds, (mts[0] << 5) + l31, kk, lane),
                 frag32(s_lds, (jts[0] << 5) + l31, kk, lane), sa0);
    sa1 = MFMA32(frag32(q_lds, (mts[1] << 5) + l31, kk, lane),
                 frag32(s_lds, (jts[1] << 5) + l31, kk, lane), sa1);
    if (ntiles == 3)
      sa2 = MFMA32(frag32(q_lds, (mts[2] << 5) + l31, kk, lane),
                   frag32(s_lds, (jts[2] << 5) + l31, kk, lane), sa2);
    f16x8 aq = frag32(q_lds, (wave << 5) + l31, kk, lane);  // own m-tile
    o0 = MFMA32(aq, wf0[kk], o0);
    o1 = MFMA32(aq, wf1[kk], o1);
  }
  __syncthreads();  // B2: all reads of k (s_lds) and q done

  // masked S -> s_lds (upper tiles never read by Sv, left stale)
#define STORE_S(ACC, MT, JT)                                                  \
  {                                                                           \
    const bool dg = ((MT) == (JT));                                           \
    _Pragma("unroll") for (int r = 0; r < 16; ++r) {                          \
      int rl = rowf(r, g);                                                    \
      float val = ACC[r];                                                     \
      if (dg && l31 > rl) val = 0.f;                                          \
      *(f16*)((char*)s_lds + swzb(((MT) << 5) + rl, ((JT) << 5) + l31)) =     \
          (f16)val;                                                           \
    }                                                                         \
  }
  STORE_S(sa0, mts[0], jts[0]);
  STORE_S(sa1, mts[1], jts[1]);
  if (ntiles == 3) STORE_S(sa2, mts[2], jts[2]);
  __syncthreads();  // B3

  // Sv: wave's own m-tile, k-range limited to the causal triangle
  const int nkk = (wave + 1) << 1;
  for (int kk = 0; kk < nkk; ++kk) {
    f16x8 as = frag32(s_lds, (wave << 5) + l31, kk, lane);
    o0 = MFMA32(as, frag32(vT, l31, kk, lane), o0);
    o1 = MFMA32(as, frag32(vT, 32 + l31, kk, lane), o1);
  }
  float* og = out + (((size_t)bh * 4096) + c * 128 + (wave << 5)) * 128 + vhalf * 64;
#pragma unroll
  for (int r = 0; r < 16; ++r) {
    int rl = rowf(r, g);
    float tg = (float)(c * 128 + (wave << 5) + rl + 1);
    og[rl * 128 + l31] = o0[r] / tg;
    og[rl * 128 + 32 + l31] = o1[r] / tg;
  }
}

// ---------------------------------------------------------------------------
// Fallback (R1, verified passing): single-kernel sequential scan.
__device__ __forceinline__ f16x8 fragr(const f16* lds, int row, int kbase, int lane) {
  int c0 = kbase + ((lane >> 4) << 3);
  return *(const f16x8*)((const char*)lds + swzb(row, c0));
}
__device__ __forceinline__ f16x8 fragkT(const f16* lds, int kbase, int col, int lane) {
  f16x8 r;
  int r0 = kbase + ((lane >> 4) << 3);
#pragma unroll
  for (int j = 0; j < 8; ++j)
    r[j] = *(const f16*)((const char*)lds + swzb(r0 + j, col));
  return r;
}

__global__ __launch_bounds__(512, 1)
void ttr_fastweight(const float* __restrict__ q, const float* __restrict__ k,
                    const float* __restrict__ v, float* __restrict__ out) {
  __shared__ f16 q_lds[128 * 128];
  __shared__ f16 k_lds[128 * 128];
  __shared__ f16 a_lds[128 * 128];
  __shared__ f16 vT_lds[16 * 128];
  __shared__ f16 wT_lds[2][16 * 128];
  const int tid = threadIdx.x;
  const int lane = tid & 63;
  const int wave = tid >> 6;
  const int vg = blockIdx.x >> 5;
  const int b = blockIdx.x & 31;
  const float* qb = q + (size_t)b * (4096 * 128);
  const float* kb = k + (size_t)b * (4096 * 128);
  const float* vb = v + (size_t)b * (4096 * 128) + vg * 16;
  float* ob = out + (size_t)b * (4096 * 128) + vg * 16;
  for (int i = tid; i < 16 * 128; i += 512) wT_lds[0][i] = (f16)0.f;
  f32x4 wacc = {0.f, 0.f, 0.f, 0.f};
  __syncthreads();
  const int colj = lane & 15;
  const int row4 = (lane >> 4) << 2;
  for (int chunk = 0; chunk < 32; ++chunk) {
    const int cur = chunk & 1, nxt = cur ^ 1;
    __syncthreads();
    {
      const float* qg = qb + (size_t)chunk * (128 * 128);
      const float* kg = kb + (size_t)chunk * (128 * 128);
      int rr = tid >> 5;
      int cc = (tid & 31) << 2;
#pragma unroll
      for (int p = 0; p < 8; ++p) {
        int row = (p << 4) + rr;
        fv4 x = *(const fv4*)(qg + row * 128 + cc);
        f16x4 h = {(f16)x[0], (f16)x[1], (f16)x[2], (f16)x[3]};
        *(f16x4*)((char*)q_lds + swzb(row, cc)) = h;
        fv4 y = *(const fv4*)(kg + row * 128 + cc);
        f16x4 h2 = {(f16)y[0], (f16)y[1], (f16)y[2], (f16)y[3]};
        *(f16x4*)((char*)k_lds + swzb(row, cc)) = h2;
      }
      const float* vgp = vb + (size_t)chunk * (128 * 128);
      int vrow = tid >> 2;
      int vp = (tid & 3) << 2;
      fv4 xv = *(const fv4*)(vgp + vrow * 128 + vp);
#pragma unroll
      for (int t = 0; t < 4; ++t)
        *(f16*)((char*)vT_lds + swzb(vp + t, vrow)) = (f16)xv[t];
    }
    __syncthreads();
    {
      int u = 0;
      for (int r = 0; r < 8; ++r) {
        for (int c2 = 0; c2 <= r; ++c2) {
          if ((u++ & 7) != wave) continue;
          f32x4 acc = {0.f, 0.f, 0.f, 0.f};
          int arow = (r << 4) + colj;
          int brow = (c2 << 4) + colj;
#pragma unroll
          for (int kk = 0; kk < 4; ++kk)
            acc = MFMA16(fragr(q_lds, arow, kk << 5, lane),
                         fragr(k_lds, brow, kk << 5, lane), acc);
#pragma unroll
          for (int t = 0; t < 4; ++t) {
            float val = acc[t];
            if (r == c2 && colj > row4 + t) val = 0.f;
            *(f16*)((char*)a_lds + swzb((r << 4) + row4 + t, (c2 << 4) + colj)) =
                (f16)val;
          }
        }
      }
      if (wave < 4) {
        int r = wave << 1;
#pragma unroll
        for (int t = 0; t < 4; ++t)
          *(f16*)((char*)a_lds +
                  swzb((r << 4) + row4 + t, ((r + 1) << 4) + colj)) = (f16)0.f;
      }
#pragma unroll
      for (int kk = 0; kk < 4; ++kk)
        wacc = MFMA16(fragr(vT_lds, colj, kk << 5, lane),
                      fragkT(k_lds, kk << 5, (wave << 4) + colj, lane), wacc);
#pragma unroll
      for (int t = 0; t < 4; ++t)
        *(f16*)((char*)wT_lds[nxt] + swzb(row4 + t, (wave << 4) + colj)) =
            (f16)wacc[t];
    }
    __syncthreads();
    {
      int r = wave;
      int qrow = (r << 4) + colj;
      f32x4 acc = {0.f, 0.f, 0.f, 0.f};
#pragma unroll
      for (int kk = 0; kk < 4; ++kk)
        acc = MFMA16(fragr(q_lds, qrow, kk << 5, lane),
                     fragr(wT_lds[cur], colj, kk << 5, lane), acc);
      int nkk = (r + 2) >> 1;
      for (int kk = 0; kk < nkk; ++kk)
        acc = MFMA16(fragr(a_lds, qrow, kk << 5, lane),
                     fragr(vT_lds, colj, kk << 5, lane), acc);
      float* og = ob + (size_t)((chunk << 7) + (r << 4)) * 128 + colj;
#pragma unroll
      for (int t = 0; t < 4; ++t) {
        int lr = row4 + t;
        float tg = (float)((chunk << 7) + (r << 4) + lr + 1);
        og[(size_t)lr * 128] = acc[t] / tg;
      }
    }
  }
}

extern "C" void kernel_launch(void* const* d_in, const int* in_sizes, int n_in,
                              void* d_out, int out_size, void* d_ws, size_t ws_size,
                              hipStream_t stream) {
  const float* q = (const float*)d_in[0];
  const float* k = (const float*)d_in[1];
  const float* v = (const float*)d_in[2];
  float* o = (float*)d_out;
  const size_t need = (size_t)2 * 32 * 32 * 16384 * sizeof(f16);  // 64 MB
  if (ws_size >= need) {
    f16* pt = (f16*)d_ws;
    f16* w = pt + (size_t)32 * 32 * 16384;
    ttr_pt<<<dim3(1024), dim3(512), 0, stream>>>(k, v, pt);
    ttr_prefix<<<dim3(256), dim3(256), 0, stream>>>(pt, w);
    ttr_out<<<dim3(2048), dim3(256), 0, stream>>>(q, k, v, w, o);
  } else {
    ttr_fastweight<<<dim3(256), dim3(512), 0, stream>>>(q, k, v, o);
  }
}